// Round 11
// baseline (2091.682 us; speedup 1.0000x reference)
//
#include <hip/hip_runtime.h>

// EmbodiedCTRNN: T=512,B=256,IN=128,H=512,BODY=64, alpha=0.1
// Round 14: per-wave release flags on the R11 base (IF$ transport, proven).
//  - R13 post-mortem: L2-local lever abandoned permanently (3rd failure).
//    Probe was eviction-racy -> spurious fast=true cross-XCD -> sc0 poll hits
//    a stale clean line in the reader's own L2 forever -> hang.
//  - This round removes block-wide release serialization instead:
//    * Each h-writer wave (kh==0, jt 0..3) drains ITS OWN stores (vmcnt(0))
//      and publishes flag[m][jt] immediately - no [F] rendezvous barrier.
//    * Body reduce+publish moves wave0 -> wave1 (non-h-writer, runs parallel
//      with h-writers), publishes flag[m][4].
//    * Reader wave ww polls member ww's flags {0..3} (+4 if ww<4), lanes l<5.
//    * 2 barriers/step ([C],[E]); WAR ordering arguments unchanged from R11.
//  - Keeps: sc0sc1 exchange transport, dense slot-major staging,
//    unconditional fragment reads, per-member pipelined poll numbering.

#define T_STEPS 512
#define NB      256
#define IN_DIM  128
#define HID     512
#define BODYD   64
#define ALPHA_F 0.1f

// ws layout (bytes) — ends exactly at 3835904 (no growth; R9 lesson)
#define WS_WH    0u          // Whh hi bf16 [512][512]   524288
#define WS_WH2   524288u     // Whh lo bf16              524288
#define WS_WI    1048576u    // Wi2h hi bf16 [512][128]  131072
#define WS_WHB   1179648u    // Wh2b hi bf16 [64][512]    65536
#define WS_WHB2  1245184u    // Wh2b lo                   65536
#define WS_WBH   1310720u    // Wb2h hi bf16 [512][64]    65536
#define WS_WBH2  1376256u    // Wb2h lo                   65536
#define WS_BIAS  1441792u    // f32 [512] bias sum         2048
#define WS_FLAG  1443840u    // 32 groups x 8 members x 128B (words 0..3 h, 4 body)
#define WS_XCHG  1476608u    // 32 groups x 73728
#define GRP_STRIDE 73728u    // h: 4x16384 (parity,part) then body: 4x2048 at +65536

#define BODY_OFF 67108864u   // T*B*H
#define FIN_OFF  75497472u   // + T*B*BODY

typedef __attribute__((ext_vector_type(8))) short bf16x8;
typedef __attribute__((ext_vector_type(4))) float f32x4;

__device__ __forceinline__ unsigned short f2bf(float f) {
    union { float f; unsigned int u; } v; v.f = f;
    unsigned int u = v.u;
    return (unsigned short)((u + 0x7fffu + ((u >> 16) & 1u)) >> 16);  // RNE
}
__device__ __forceinline__ float b2f(unsigned short h) {
    union { unsigned int u; float f; } v; v.u = ((unsigned int)h) << 16;
    return v.f;
}
__device__ __forceinline__ bf16x8 ldfrag(const unsigned short* p) {
    return *reinterpret_cast<const bf16x8*>(p);
}

// fine-grained coherent (IF$-level) access: sc0 sc1 = bypass L1 and L2.
#define LD128_SYSP(dst, ptr)                                           \
    asm volatile("global_load_dwordx4 %0, %1, off sc0 sc1"             \
                 : "=v"(dst) : "v"(ptr) : "memory")
#define ST16_SYS(base, imm, val)                                           \
    asm volatile("global_store_short %0, %1, off offset:" #imm " sc0 sc1"  \
                 :: "v"(base), "v"((unsigned int)(val)) : "memory")

// ---------------- kernel 0: init / convert ----------------
__global__ void init_kernel(const float* __restrict__ Wi2h, const float* __restrict__ bi2h,
                            const float* __restrict__ Whh,  const float* __restrict__ bh2h,
                            const float* __restrict__ Wb2h, const float* __restrict__ bb2h,
                            const float* __restrict__ Wh2b,
                            unsigned char* __restrict__ ws) {
    int idx = blockIdx.x * blockDim.x + threadIdx.x;
    int stride = gridDim.x * blockDim.x;
    unsigned short* WH  = (unsigned short*)(ws + WS_WH);
    unsigned short* WH2 = (unsigned short*)(ws + WS_WH2);
    for (int i = idx; i < HID * HID; i += stride) {
        float w = Whh[i]; unsigned short h = f2bf(w);
        WH[i] = h; WH2[i] = f2bf(w - b2f(h));
    }
    unsigned short* WI = (unsigned short*)(ws + WS_WI);
    for (int i = idx; i < HID * IN_DIM; i += stride) WI[i] = f2bf(Wi2h[i]);
    unsigned short* WHB  = (unsigned short*)(ws + WS_WHB);
    unsigned short* WHB2 = (unsigned short*)(ws + WS_WHB2);
    for (int i = idx; i < BODYD * HID; i += stride) {
        float w = Wh2b[i]; unsigned short h = f2bf(w);
        WHB[i] = h; WHB2[i] = f2bf(w - b2f(h));
    }
    unsigned short* WBH  = (unsigned short*)(ws + WS_WBH);
    unsigned short* WBH2 = (unsigned short*)(ws + WS_WBH2);
    for (int i = idx; i < HID * BODYD; i += stride) {
        float w = Wb2h[i]; unsigned short h = f2bf(w);
        WBH[i] = h; WBH2[i] = f2bf(w - b2f(h));
    }
    float* BS = (float*)(ws + WS_BIAS);
    for (int i = idx; i < HID; i += stride) BS[i] = bi2h[i] + bh2h[i] + bb2h[i];
    // zero flags + exchange (h0=0, b0=0); stays in bounds
    unsigned int* Z = (unsigned int*)(ws + WS_FLAG);
    int zn = (int)((WS_XCHG + 32u * GRP_STRIDE - WS_FLAG) / 4u);
    for (int i = idx; i < zn; i += stride) Z[i] = 0u;
}

// ---------------- kernel 1: x projection -> d_out hidden region ----------------
__global__ __launch_bounds__(256) void xproj_kernel(const float* __restrict__ x,
                                                    float* __restrict__ out,
                                                    const unsigned char* __restrict__ ws) {
    const unsigned short* WI = (const unsigned short*)(ws + WS_WI);
    const float* BS = (const float*)(ws + WS_BIAS);
    int tid = threadIdx.x;
    int l = tid & 63, ww = tid >> 6;
    int lr = l & 15, lq = l >> 4;
    int m0 = blockIdx.x * 64 + ww * 16;
    int n0 = blockIdx.y * 128;

    bf16x8 a[4];
    const float* xr = x + (size_t)(m0 + lr) * IN_DIM + lq * 8;
#pragma unroll
    for (int kt = 0; kt < 4; ++kt) {
        bf16x8 t;
#pragma unroll
        for (int e = 0; e < 8; ++e) t[e] = (short)f2bf(xr[kt * 32 + e]);
        a[kt] = t;
    }
    f32x4 acc[8];
#pragma unroll
    for (int jt = 0; jt < 8; ++jt) acc[jt] = (f32x4){0.f, 0.f, 0.f, 0.f};
#pragma unroll
    for (int jt = 0; jt < 8; ++jt) {
        const unsigned short* wr = WI + (size_t)(n0 + jt * 16 + lr) * IN_DIM + lq * 8;
#pragma unroll
        for (int kt = 0; kt < 4; ++kt) {
            bf16x8 b = ldfrag(wr + kt * 32);
            acc[jt] = __builtin_amdgcn_mfma_f32_16x16x32_bf16(a[kt], b, acc[jt], 0, 0, 0);
        }
    }
#pragma unroll
    for (int jt = 0; jt < 8; ++jt) {
        int n = n0 + jt * 16 + lr;
        float bs = BS[n];
#pragma unroll
        for (int i = 0; i < 4; ++i) {
            int mm = m0 + lq * 4 + i;
            out[(size_t)mm * HID + n] = acc[jt][i] + bs;
        }
    }
}

// ---------------- kernel 2: recurrent scan ----------------
__global__ __launch_bounds__(512, 2) void rnn_kernel(float* __restrict__ out,
                                                     unsigned char* __restrict__ ws,
                                                     const float* __restrict__ bh2b,
                                                     const float* __restrict__ mask) {
    const int tid = threadIdx.x;
    const int l = tid & 63;
    const int ww = tid >> 6;
    const int jt = ww >> 1;
    const int kh = ww & 1;
    const int lr = l & 15;
    const int lq = l >> 4;

    const int w = blockIdx.x;
    const int xcd = w & 7;        // grouping heuristic only; sync is placement-safe
    const int slot = w >> 3;
    const int g = (slot >> 3) * 8 + xcd;   // group 0..31
    const int m = slot & 7;                // member 0..7

    // dense slot-major staging: H1 [64 chunks][8 rows x 16B] @0 (8KB),
    // H2 @8192, B1 [8 chunks][8 rows x 16B] @16384 (1KB), B2 @17408
    __shared__ f32x4 stg[1152];           // 18432 B
    __shared__ f32x4 lds_h[4][64];
    __shared__ f32x4 lds_b[8][64];
    unsigned char* stgb = (unsigned char*)stg;

    // resident weight fragments (plain cached loads; read-only, pre-loop)
    const unsigned short* WH  = (const unsigned short*)(ws + WS_WH);
    const unsigned short* WH2 = (const unsigned short*)(ws + WS_WH2);
    bf16x8 wh[8], wh2[8];
    const int wrow = m * 64 + jt * 16 + lr;
    {
        const unsigned short* p1 = WH  + (size_t)wrow * HID + kh * 256 + lq * 8;
        const unsigned short* p2 = WH2 + (size_t)wrow * HID + kh * 256 + lq * 8;
#pragma unroll
        for (int r = 0; r < 8; ++r) { wh[r] = ldfrag(p1 + r * 32); wh2[r] = ldfrag(p2 + r * 32); }
    }
    const unsigned short* WBH  = (const unsigned short*)(ws + WS_WBH);
    const unsigned short* WBH2 = (const unsigned short*)(ws + WS_WBH2);
    bf16x8 wbh  = ldfrag(WBH  + (size_t)wrow * BODYD + kh * 32 + lq * 8);
    bf16x8 wbh2 = ldfrag(WBH2 + (size_t)wrow * BODYD + kh * 32 + lq * 8);

    bf16x8 whb0 = {}, whb1 = {}, whb0l = {}, whb1l = {};
    float maskv = 0.f, bhbv = 0.f;
    const int kt0 = kh * 8 + 2 * jt;
    if (m < 4) {
        const unsigned short* WHB  = (const unsigned short*)(ws + WS_WHB);
        const unsigned short* WHB2 = (const unsigned short*)(ws + WS_WHB2);
        const int brow = m * 16 + lr;
        whb0  = ldfrag(WHB  + (size_t)brow * HID + kt0 * 32 + lq * 8);
        whb1  = ldfrag(WHB  + (size_t)brow * HID + (kt0 + 1) * 32 + lq * 8);
        whb0l = ldfrag(WHB2 + (size_t)brow * HID + kt0 * 32 + lq * 8);
        whb1l = ldfrag(WHB2 + (size_t)brow * HID + (kt0 + 1) * 32 + lq * 8);
        maskv = mask[m * 16 + lr];
        bhbv  = bh2b[m * 16 + lr];
    }

    unsigned char* xg = ws + WS_XCHG + (size_t)g * GRP_STRIDE;
    unsigned int* flg_self = (unsigned int*)(ws + WS_FLAG) + g * 256 + m * 32;
    unsigned int* flg_base = (unsigned int*)(ws + WS_FLAG) + g * 256;

    float hst[4] = {0.f, 0.f, 0.f, 0.f};
    float bst[4] = {0.f, 0.f, 0.f, 0.f};

    const int jg = m * 64 + jt * 16 + lr;

    // ---- loader geometry: wave ww loads member ww's slice ----
    const int c8 = l >> 3;                 // 0..7 col-chunk within member
    const int r8 = l & 7;                  // 0..7 row
    const unsigned char* ghb = xg + (size_t)r8 * 1024 + ww * 128 + c8 * 16;
    unsigned char* sth = stgb + (ww * 8 + c8) * 128 + r8 * 16;      // H1 dest; H2 = +8192
    const unsigned char* gbb = xg + 65536u + (size_t)r8 * 128 + ww * 32 + ((l >> 3) & 1) * 16;
    unsigned char* stb = stgb + 16384 + (ww * 2 + ((l >> 3) & 1)) * 128 + r8 * 16;
    const bool bl = (ww < 4) && (l < 16);

    // ---- fragment-read geometry (dense; row clamped (lr&7): pad lanes lr>=8
    // read DUPLICATES of rows 0..7 -> C rows 8..15 garbage, never stored (lq<2).
    const unsigned char* fhb = stgb + kh * 4096 + lq * 128 + (lr & 7) * 16;
    const unsigned char* fbb = stgb + 16384 + (kh * 4 + lq) * 128 + (lr & 7) * 16;

    for (int t = 0; t < T_STEPS; ++t) {
        const int p = t & 1;

        // ---- per-wave pipelined poll: wave ww waits for member ww's step-t
        // publication. Member ww publishes via 4 per-wave h-flags (words 0..3)
        // + 1 body flag (word 4, only members m<4). Lanes l<4 poll h-flags;
        // lane 4 polls body flag when ww<4. Same proven system-scope channel
        // and numbering as R11 (flag value t+1 stored at end of step t).
        if (t > 0) {
            const bool need = (l < 4) || ((l == 4) && (ww < 4));
            if (need) {
                unsigned int* f = flg_base + ww * 32 + l;
                while (__hip_atomic_load(f, __ATOMIC_RELAXED,
                                         __HIP_MEMORY_SCOPE_SYSTEM) < (unsigned int)t) {
                    __builtin_amdgcn_s_sleep(1);
                }
            }
        }

        // ---- load member ww's slice -> dense LDS staging ----
        const unsigned char* ghp = ghb + (size_t)p * 32768u;
        f32x4 vh1, vh2, vb1, vb2;
        LD128_SYSP(vh1, ghp);
        LD128_SYSP(vh2, ghp + 16384);
        if (bl) {
            const unsigned char* gbp = gbb + (size_t)p * 4096u;
            LD128_SYSP(vb1, gbp);
            LD128_SYSP(vb2, gbp + 2048);
        }
        asm volatile("s_waitcnt vmcnt(0)" ::: "memory");
        __builtin_amdgcn_sched_barrier(0);
        *(f32x4*)sth = vh1;
        *(f32x4*)(sth + 8192) = vh2;
        if (bl) { *(f32x4*)stb = vb1; *(f32x4*)(stb + 1024) = vb2; }
        __syncthreads();                               // [C] stage complete

        // ---- fragments from dense LDS (unconditional; lane pairs (l,l+8)
        // broadcast the same address -> conflict-free) ----
        bf16x8 a[8], a2[8], ab1, ab2;
#pragma unroll
        for (int r = 0; r < 8; ++r) {
            a[r]  = *(const bf16x8*)(fhb + r * 512);
            a2[r] = *(const bf16x8*)(fhb + 8192 + r * 512);
        }
        ab1 = *(const bf16x8*)fbb;
        ab2 = *(const bf16x8*)(fbb + 1024);

        // xp prefetch for this step (hidden under MFMAs)
        float cpre[4] = {0.f, 0.f, 0.f, 0.f};
        float* op = out + (size_t)t * (NB * HID) + (size_t)(g * 8) * HID + jg;
        if (!kh && lq < 2) {
#pragma unroll
            for (int i = 0; i < 4; ++i)
                cpre[i] = __builtin_nontemporal_load(op + (size_t)(lq * 4 + i) * HID);
        }

        // 3 independent accumulator chains
        f32x4 acc0 = {0.f, 0.f, 0.f, 0.f}, acc1 = acc0, acc2 = acc0;
#pragma unroll
        for (int r = 0; r < 8; ++r) acc0 = __builtin_amdgcn_mfma_f32_16x16x32_bf16(a[r],  wh[r],  acc0, 0, 0, 0);
#pragma unroll
        for (int r = 0; r < 8; ++r) acc1 = __builtin_amdgcn_mfma_f32_16x16x32_bf16(a2[r], wh[r],  acc1, 0, 0, 0);
#pragma unroll
        for (int r = 0; r < 8; ++r) acc2 = __builtin_amdgcn_mfma_f32_16x16x32_bf16(a[r],  wh2[r], acc2, 0, 0, 0);
        acc0 = __builtin_amdgcn_mfma_f32_16x16x32_bf16(ab1, wbh,  acc0, 0, 0, 0);
        acc1 = __builtin_amdgcn_mfma_f32_16x16x32_bf16(ab2, wbh,  acc1, 0, 0, 0);
        acc2 = __builtin_amdgcn_mfma_f32_16x16x32_bf16(ab1, wbh2, acc2, 0, 0, 0);
        f32x4 acc = acc0 + acc1 + acc2;

        f32x4 bacc = {0.f, 0.f, 0.f, 0.f};
        if (m < 4) {
            bf16x8 s0, s1, u0, u1;   // static select (avoid runtime-indexed regs -> scratch)
            if      (jt == 0) { s0 = a[0]; s1 = a[1]; u0 = a2[0]; u1 = a2[1]; }
            else if (jt == 1) { s0 = a[2]; s1 = a[3]; u0 = a2[2]; u1 = a2[3]; }
            else if (jt == 2) { s0 = a[4]; s1 = a[5]; u0 = a2[4]; u1 = a2[5]; }
            else              { s0 = a[6]; s1 = a[7]; u0 = a2[6]; u1 = a2[7]; }
            f32x4 b0 = {0.f, 0.f, 0.f, 0.f}, b1 = b0;
            b0 = __builtin_amdgcn_mfma_f32_16x16x32_bf16(s0, whb0,  b0, 0, 0, 0);
            b1 = __builtin_amdgcn_mfma_f32_16x16x32_bf16(s1, whb1,  b1, 0, 0, 0);
            b0 = __builtin_amdgcn_mfma_f32_16x16x32_bf16(u0, whb0,  b0, 0, 0, 0);
            b1 = __builtin_amdgcn_mfma_f32_16x16x32_bf16(u1, whb1,  b1, 0, 0, 0);
            b0 = __builtin_amdgcn_mfma_f32_16x16x32_bf16(s0, whb0l, b0, 0, 0, 0);
            b1 = __builtin_amdgcn_mfma_f32_16x16x32_bf16(s1, whb1l, b1, 0, 0, 0);
            bacc = b0 + b1;
        }

        if (kh) lds_h[jt][l] = acc;
        if (m < 4) lds_b[ww][l] = bacc;
        __syncthreads();                               // [E] partials ready

        // ---- h-writer waves (kh==0): compute, store exchange, drain OWN
        // stores, publish per-wave flag, then NT outputs. No block barrier.
        if (!kh) {
            f32x4 oth = lds_h[jt][l];
            f32x4 sum = acc + oth;
            float hnv[4] = {0.f, 0.f, 0.f, 0.f};
            if (lq < 2) {
                unsigned short* q1 = (unsigned short*)(xg + ((p ^ 1) * 2 + 0) * 16384)
                                     + (lq * 4) * HID + jg;
                unsigned short* q2 = (unsigned short*)(xg + ((p ^ 1) * 2 + 1) * 16384)
                                     + (lq * 4) * HID + jg;
                unsigned short hh[4], hl[4];
#pragma unroll
                for (int i = 0; i < 4; ++i) {
                    float pre = sum[i] + cpre[i];
                    float rl = fmaxf(pre, 0.f);
                    float hv = 0.9f * hst[i] + 0.1f * rl;
                    hst[i] = hv; hnv[i] = hv;
                    hh[i] = f2bf(hv); hl[i] = f2bf(hv - b2f(hh[i]));
                }
                // write-through to IF$ (visible cross-XCD once vmcnt-drained)
                ST16_SYS(q1, 0,    hh[0]); ST16_SYS(q1, 1024, hh[1]);
                ST16_SYS(q1, 2048, hh[2]); ST16_SYS(q1, 3072, hh[3]);
                ST16_SYS(q2, 0,    hl[0]); ST16_SYS(q2, 1024, hl[1]);
                ST16_SYS(q2, 2048, hl[2]); ST16_SYS(q2, 3072, hl[3]);
            }
            // per-wave release: drain THIS wave's stores, then flag[m][jt]
            asm volatile("s_waitcnt vmcnt(0)" ::: "memory");
            if (l == 0) {
                __hip_atomic_store(flg_self + jt, (unsigned int)(t + 1),
                                   __ATOMIC_RELAXED, __HIP_MEMORY_SCOPE_SYSTEM);
            }
            // deferred NT output writes (not needed by peers) overlap peers' polls
            if (lq < 2) {
#pragma unroll
                for (int i = 0; i < 4; ++i)
                    __builtin_nontemporal_store(hnv[i], op + (size_t)(lq * 4 + i) * HID);
            }
        }

        // ---- body on wave 1 (non-h-writer: parallel with h-writer waves) ----
        if (ww == 1 && m < 4) {
            f32x4 bs = lds_b[0][l];
#pragma unroll
            for (int s = 1; s < 8; ++s) bs += lds_b[s][l];
            float bnv[4] = {0.f, 0.f, 0.f, 0.f};
            int jb = m * 16 + lr;
            if (lq < 2) {
                unsigned short* r1 = (unsigned short*)(xg + 65536 + ((p ^ 1) * 2 + 0) * 2048)
                                     + (lq * 4) * BODYD + jb;
                unsigned short* r2 = (unsigned short*)(xg + 65536 + ((p ^ 1) * 2 + 1) * 2048)
                                     + (lq * 4) * BODYD + jb;
                unsigned short bh[4], blo[4];
#pragma unroll
                for (int i = 0; i < 4; ++i) {
                    float bn = bst[i] * maskv + ALPHA_F * (bs[i] + bhbv);
                    bst[i] = bn; bnv[i] = bn;
                    bh[i] = f2bf(bn); blo[i] = f2bf(bn - b2f(bh[i]));
                }
                ST16_SYS(r1, 0,   bh[0]);  ST16_SYS(r1, 128, bh[1]);
                ST16_SYS(r1, 256, bh[2]);  ST16_SYS(r1, 384, bh[3]);
                ST16_SYS(r2, 0,   blo[0]); ST16_SYS(r2, 128, blo[1]);
                ST16_SYS(r2, 256, blo[2]); ST16_SYS(r2, 384, blo[3]);
            }
            asm volatile("s_waitcnt vmcnt(0)" ::: "memory");
            if (l == 0) {
                __hip_atomic_store(flg_self + 4, (unsigned int)(t + 1),
                                   __ATOMIC_RELAXED, __HIP_MEMORY_SCOPE_SYSTEM);
            }
            if (lq < 2) {
#pragma unroll
                for (int i = 0; i < 4; ++i) {
                    int mi = lq * 4 + i;
                    __builtin_nontemporal_store(
                        bnv[i],
                        out + BODY_OFF + (size_t)t * (NB * BODYD)
                            + (size_t)(g * 8 + mi) * BODYD + jb);
                }
            }
        }
        // no [F] barrier: [E] orders this step's staging/lds reads before next
        // step's writes; per-wave flags gate peers' next-step exchange reads.
    }

    // h_fin = final h
    if (!kh && lq < 2) {
#pragma unroll
        for (int i = 0; i < 4; ++i) {
            int mi = lq * 4 + i;
            __builtin_nontemporal_store(hst[i], out + FIN_OFF + (size_t)(g * 8 + mi) * HID + jg);
        }
    }
}

extern "C" void kernel_launch(void* const* d_in, const int* in_sizes, int n_in,
                              void* d_out, int out_size, void* d_ws, size_t ws_size,
                              hipStream_t stream) {
    const float* x    = (const float*)d_in[0];
    const float* Wi2h = (const float*)d_in[1];
    const float* bi2h = (const float*)d_in[2];
    const float* Whh  = (const float*)d_in[3];
    const float* bh2h = (const float*)d_in[4];
    const float* Wb2h = (const float*)d_in[5];
    const float* bb2h = (const float*)d_in[6];
    const float* Wh2b = (const float*)d_in[7];
    const float* bh2b = (const float*)d_in[8];
    const float* mask = (const float*)d_in[9];
    float* out = (float*)d_out;
    unsigned char* ws = (unsigned char*)d_ws;

    init_kernel<<<256, 256, 0, stream>>>(Wi2h, bi2h, Whh, bh2h, Wb2h, bb2h, Wh2b, ws);
    xproj_kernel<<<dim3(2048, 4), 256, 0, stream>>>(x, out, ws);

    void* kargs[] = { (void*)&out, (void*)&ws, (void*)&bh2b, (void*)&mask };
    hipLaunchCooperativeKernel((void*)rnn_kernel, dim3(256), dim3(512), kargs, 0, stream);
}

// Round 12
// 1733.626 us; speedup vs baseline: 1.2065x; 1.2065x over previous
//
#include <hip/hip_runtime.h>

// EmbodiedCTRNN: T=512,B=256,IN=128,H=512,BODY=64, alpha=0.1
// Round 15: counter-based release on the R11 base.
//  - R14 post-mortem (REGRESSED +315us): 5 per-wave flags share one 128B line
//    -> 5 serialized sc0sc1 partial-sector stores per member per step + 5-flag
//    observe. Lesson: exactly ONE release store per member.
//  - This round: keep R11's reader protocol verbatim (one flag per member,
//    per-member pipelined poll). Replace [F]-barrier+tid0-flag with:
//    each h-writer wave drains ITS OWN stores (vmcnt 0), bumps an LDS
//    counter; the LAST writer wave (count==4*(t+1)) publishes the single
//    member flag. Flag goes out at max(writer drains) - no block barrier,
//    no non-writer wait, no tid0 wakeup. 2 barriers/step ([C],[E]).
//  - WAR safety unchanged from R6/R11: [C] requires all 8 per-wave polls
//    (flags >= t) before any step-t exchange store; data-before-flag holds
//    since every writer increments only after its own vmcnt(0).
//  - Keeps: sc0sc1 IF$ transport (L2-local lever abandoned after 3 failures),
//    dense slot-major staging, unconditional fragment reads, body on wave 0.

#define T_STEPS 512
#define NB      256
#define IN_DIM  128
#define HID     512
#define BODYD   64
#define ALPHA_F 0.1f

// ws layout (bytes) — ends exactly at 3835904 (no growth; R9 lesson)
#define WS_WH    0u          // Whh hi bf16 [512][512]   524288
#define WS_WH2   524288u     // Whh lo bf16              524288
#define WS_WI    1048576u    // Wi2h hi bf16 [512][128]  131072
#define WS_WHB   1179648u    // Wh2b hi bf16 [64][512]    65536
#define WS_WHB2  1245184u    // Wh2b lo                   65536
#define WS_WBH   1310720u    // Wb2h hi bf16 [512][64]    65536
#define WS_WBH2  1376256u    // Wb2h lo                   65536
#define WS_BIAS  1441792u    // f32 [512] bias sum         2048
#define WS_FLAG  1443840u    // 32 groups x 8 members x 128B = 32768
#define WS_XCHG  1476608u    // 32 groups x 73728
#define GRP_STRIDE 73728u    // h: 4x16384 (parity,part) then body: 4x2048 at +65536

#define BODY_OFF 67108864u   // T*B*H
#define FIN_OFF  75497472u   // + T*B*BODY

typedef __attribute__((ext_vector_type(8))) short bf16x8;
typedef __attribute__((ext_vector_type(4))) float f32x4;

__device__ __forceinline__ unsigned short f2bf(float f) {
    union { float f; unsigned int u; } v; v.f = f;
    unsigned int u = v.u;
    return (unsigned short)((u + 0x7fffu + ((u >> 16) & 1u)) >> 16);  // RNE
}
__device__ __forceinline__ float b2f(unsigned short h) {
    union { unsigned int u; float f; } v; v.u = ((unsigned int)h) << 16;
    return v.f;
}
__device__ __forceinline__ bf16x8 ldfrag(const unsigned short* p) {
    return *reinterpret_cast<const bf16x8*>(p);
}

// fine-grained coherent (IF$-level) access: sc0 sc1 = bypass L1 and L2.
#define LD128_SYSP(dst, ptr)                                           \
    asm volatile("global_load_dwordx4 %0, %1, off sc0 sc1"             \
                 : "=v"(dst) : "v"(ptr) : "memory")
#define ST16_SYS(base, imm, val)                                           \
    asm volatile("global_store_short %0, %1, off offset:" #imm " sc0 sc1"  \
                 :: "v"(base), "v"((unsigned int)(val)) : "memory")

// ---------------- kernel 0: init / convert ----------------
__global__ void init_kernel(const float* __restrict__ Wi2h, const float* __restrict__ bi2h,
                            const float* __restrict__ Whh,  const float* __restrict__ bh2h,
                            const float* __restrict__ Wb2h, const float* __restrict__ bb2h,
                            const float* __restrict__ Wh2b,
                            unsigned char* __restrict__ ws) {
    int idx = blockIdx.x * blockDim.x + threadIdx.x;
    int stride = gridDim.x * blockDim.x;
    unsigned short* WH  = (unsigned short*)(ws + WS_WH);
    unsigned short* WH2 = (unsigned short*)(ws + WS_WH2);
    for (int i = idx; i < HID * HID; i += stride) {
        float w = Whh[i]; unsigned short h = f2bf(w);
        WH[i] = h; WH2[i] = f2bf(w - b2f(h));
    }
    unsigned short* WI = (unsigned short*)(ws + WS_WI);
    for (int i = idx; i < HID * IN_DIM; i += stride) WI[i] = f2bf(Wi2h[i]);
    unsigned short* WHB  = (unsigned short*)(ws + WS_WHB);
    unsigned short* WHB2 = (unsigned short*)(ws + WS_WHB2);
    for (int i = idx; i < BODYD * HID; i += stride) {
        float w = Wh2b[i]; unsigned short h = f2bf(w);
        WHB[i] = h; WHB2[i] = f2bf(w - b2f(h));
    }
    unsigned short* WBH  = (unsigned short*)(ws + WS_WBH);
    unsigned short* WBH2 = (unsigned short*)(ws + WS_WBH2);
    for (int i = idx; i < HID * BODYD; i += stride) {
        float w = Wb2h[i]; unsigned short h = f2bf(w);
        WBH[i] = h; WBH2[i] = f2bf(w - b2f(h));
    }
    float* BS = (float*)(ws + WS_BIAS);
    for (int i = idx; i < HID; i += stride) BS[i] = bi2h[i] + bh2h[i] + bb2h[i];
    // zero flags + exchange (h0=0, b0=0); stays in bounds
    unsigned int* Z = (unsigned int*)(ws + WS_FLAG);
    int zn = (int)((WS_XCHG + 32u * GRP_STRIDE - WS_FLAG) / 4u);
    for (int i = idx; i < zn; i += stride) Z[i] = 0u;
}

// ---------------- kernel 1: x projection -> d_out hidden region ----------------
__global__ __launch_bounds__(256) void xproj_kernel(const float* __restrict__ x,
                                                    float* __restrict__ out,
                                                    const unsigned char* __restrict__ ws) {
    const unsigned short* WI = (const unsigned short*)(ws + WS_WI);
    const float* BS = (const float*)(ws + WS_BIAS);
    int tid = threadIdx.x;
    int l = tid & 63, ww = tid >> 6;
    int lr = l & 15, lq = l >> 4;
    int m0 = blockIdx.x * 64 + ww * 16;
    int n0 = blockIdx.y * 128;

    bf16x8 a[4];
    const float* xr = x + (size_t)(m0 + lr) * IN_DIM + lq * 8;
#pragma unroll
    for (int kt = 0; kt < 4; ++kt) {
        bf16x8 t;
#pragma unroll
        for (int e = 0; e < 8; ++e) t[e] = (short)f2bf(xr[kt * 32 + e]);
        a[kt] = t;
    }
    f32x4 acc[8];
#pragma unroll
    for (int jt = 0; jt < 8; ++jt) acc[jt] = (f32x4){0.f, 0.f, 0.f, 0.f};
#pragma unroll
    for (int jt = 0; jt < 8; ++jt) {
        const unsigned short* wr = WI + (size_t)(n0 + jt * 16 + lr) * IN_DIM + lq * 8;
#pragma unroll
        for (int kt = 0; kt < 4; ++kt) {
            bf16x8 b = ldfrag(wr + kt * 32);
            acc[jt] = __builtin_amdgcn_mfma_f32_16x16x32_bf16(a[kt], b, acc[jt], 0, 0, 0);
        }
    }
#pragma unroll
    for (int jt = 0; jt < 8; ++jt) {
        int n = n0 + jt * 16 + lr;
        float bs = BS[n];
#pragma unroll
        for (int i = 0; i < 4; ++i) {
            int mm = m0 + lq * 4 + i;
            out[(size_t)mm * HID + n] = acc[jt][i] + bs;
        }
    }
}

// ---------------- kernel 2: recurrent scan ----------------
__global__ __launch_bounds__(512, 2) void rnn_kernel(float* __restrict__ out,
                                                     unsigned char* __restrict__ ws,
                                                     const float* __restrict__ bh2b,
                                                     const float* __restrict__ mask) {
    const int tid = threadIdx.x;
    const int l = tid & 63;
    const int ww = tid >> 6;
    const int jt = ww >> 1;
    const int kh = ww & 1;
    const int lr = l & 15;
    const int lq = l >> 4;

    const int w = blockIdx.x;
    const int xcd = w & 7;        // grouping heuristic only; sync is placement-safe
    const int slot = w >> 3;
    const int g = (slot >> 3) * 8 + xcd;   // group 0..31
    const int m = slot & 7;                // member 0..7

    // dense slot-major staging: H1 [64 chunks][8 rows x 16B] @0 (8KB),
    // H2 @8192, B1 [8 chunks][8 rows x 16B] @16384 (1KB), B2 @17408
    __shared__ f32x4 stg[1152];           // 18432 B
    __shared__ f32x4 lds_h[4][64];
    __shared__ f32x4 lds_b[8][64];
    __shared__ unsigned int rel_cnt;      // monotonic release counter
    unsigned char* stgb = (unsigned char*)stg;

    if (tid == 0) rel_cnt = 0u;           // consumed first after [C]+[E] of t=0

    // resident weight fragments (plain cached loads; read-only, pre-loop)
    const unsigned short* WH  = (const unsigned short*)(ws + WS_WH);
    const unsigned short* WH2 = (const unsigned short*)(ws + WS_WH2);
    bf16x8 wh[8], wh2[8];
    const int wrow = m * 64 + jt * 16 + lr;
    {
        const unsigned short* p1 = WH  + (size_t)wrow * HID + kh * 256 + lq * 8;
        const unsigned short* p2 = WH2 + (size_t)wrow * HID + kh * 256 + lq * 8;
#pragma unroll
        for (int r = 0; r < 8; ++r) { wh[r] = ldfrag(p1 + r * 32); wh2[r] = ldfrag(p2 + r * 32); }
    }
    const unsigned short* WBH  = (const unsigned short*)(ws + WS_WBH);
    const unsigned short* WBH2 = (const unsigned short*)(ws + WS_WBH2);
    bf16x8 wbh  = ldfrag(WBH  + (size_t)wrow * BODYD + kh * 32 + lq * 8);
    bf16x8 wbh2 = ldfrag(WBH2 + (size_t)wrow * BODYD + kh * 32 + lq * 8);

    bf16x8 whb0 = {}, whb1 = {}, whb0l = {}, whb1l = {};
    float maskv = 0.f, bhbv = 0.f;
    const int kt0 = kh * 8 + 2 * jt;
    if (m < 4) {
        const unsigned short* WHB  = (const unsigned short*)(ws + WS_WHB);
        const unsigned short* WHB2 = (const unsigned short*)(ws + WS_WHB2);
        const int brow = m * 16 + lr;
        whb0  = ldfrag(WHB  + (size_t)brow * HID + kt0 * 32 + lq * 8);
        whb1  = ldfrag(WHB  + (size_t)brow * HID + (kt0 + 1) * 32 + lq * 8);
        whb0l = ldfrag(WHB2 + (size_t)brow * HID + kt0 * 32 + lq * 8);
        whb1l = ldfrag(WHB2 + (size_t)brow * HID + (kt0 + 1) * 32 + lq * 8);
        maskv = mask[m * 16 + lr];
        bhbv  = bh2b[m * 16 + lr];
    }

    unsigned char* xg = ws + WS_XCHG + (size_t)g * GRP_STRIDE;
    unsigned int* flg_self = (unsigned int*)(ws + WS_FLAG) + g * 256 + m * 32;
    unsigned int* flg_base = (unsigned int*)(ws + WS_FLAG) + g * 256;
    unsigned int* flg_mine = flg_base + ww * 32;   // wave ww polls member ww

    float hst[4] = {0.f, 0.f, 0.f, 0.f};
    float bst[4] = {0.f, 0.f, 0.f, 0.f};

    const int jg = m * 64 + jt * 16 + lr;

    // ---- loader geometry: wave ww loads member ww's slice ----
    const int c8 = l >> 3;                 // 0..7 col-chunk within member
    const int r8 = l & 7;                  // 0..7 row
    const unsigned char* ghb = xg + (size_t)r8 * 1024 + ww * 128 + c8 * 16;
    unsigned char* sth = stgb + (ww * 8 + c8) * 128 + r8 * 16;      // H1 dest; H2 = +8192
    const unsigned char* gbb = xg + 65536u + (size_t)r8 * 128 + ww * 32 + ((l >> 3) & 1) * 16;
    unsigned char* stb = stgb + 16384 + (ww * 2 + ((l >> 3) & 1)) * 128 + r8 * 16;
    const bool bl = (ww < 4) && (l < 16);

    // ---- fragment-read geometry (dense; row clamped (lr&7): pad lanes lr>=8
    // read DUPLICATES of rows 0..7 -> C rows 8..15 garbage, never stored (lq<2).
    const unsigned char* fhb = stgb + kh * 4096 + lq * 128 + (lr & 7) * 16;
    const unsigned char* fbb = stgb + 16384 + (kh * 4 + lq) * 128 + (lr & 7) * 16;

    for (int t = 0; t < T_STEPS; ++t) {
        const int p = t & 1;

        // ---- per-member pipelined poll: wave ww waits for member ww's
        // step-t publication (single flag, value t+1 stored end of step t).
        if (t > 0) {
            while (__hip_atomic_load(flg_mine, __ATOMIC_RELAXED,
                                     __HIP_MEMORY_SCOPE_SYSTEM) < (unsigned int)t) {
                __builtin_amdgcn_s_sleep(1);
            }
        }

        // ---- load member ww's slice -> dense LDS staging ----
        const unsigned char* ghp = ghb + (size_t)p * 32768u;
        f32x4 vh1, vh2, vb1, vb2;
        LD128_SYSP(vh1, ghp);
        LD128_SYSP(vh2, ghp + 16384);
        if (bl) {
            const unsigned char* gbp = gbb + (size_t)p * 4096u;
            LD128_SYSP(vb1, gbp);
            LD128_SYSP(vb2, gbp + 2048);
        }
        asm volatile("s_waitcnt vmcnt(0)" ::: "memory");
        __builtin_amdgcn_sched_barrier(0);
        *(f32x4*)sth = vh1;
        *(f32x4*)(sth + 8192) = vh2;
        if (bl) { *(f32x4*)stb = vb1; *(f32x4*)(stb + 1024) = vb2; }
        __syncthreads();                               // [C] stage complete

        // ---- fragments from dense LDS (unconditional; lane pairs (l,l+8)
        // broadcast the same address -> conflict-free) ----
        bf16x8 a[8], a2[8], ab1, ab2;
#pragma unroll
        for (int r = 0; r < 8; ++r) {
            a[r]  = *(const bf16x8*)(fhb + r * 512);
            a2[r] = *(const bf16x8*)(fhb + 8192 + r * 512);
        }
        ab1 = *(const bf16x8*)fbb;
        ab2 = *(const bf16x8*)(fbb + 1024);

        // xp prefetch for this step (hidden under MFMAs)
        float cpre[4] = {0.f, 0.f, 0.f, 0.f};
        float* op = out + (size_t)t * (NB * HID) + (size_t)(g * 8) * HID + jg;
        if (!kh && lq < 2) {
#pragma unroll
            for (int i = 0; i < 4; ++i)
                cpre[i] = __builtin_nontemporal_load(op + (size_t)(lq * 4 + i) * HID);
        }

        // 3 independent accumulator chains
        f32x4 acc0 = {0.f, 0.f, 0.f, 0.f}, acc1 = acc0, acc2 = acc0;
#pragma unroll
        for (int r = 0; r < 8; ++r) acc0 = __builtin_amdgcn_mfma_f32_16x16x32_bf16(a[r],  wh[r],  acc0, 0, 0, 0);
#pragma unroll
        for (int r = 0; r < 8; ++r) acc1 = __builtin_amdgcn_mfma_f32_16x16x32_bf16(a2[r], wh[r],  acc1, 0, 0, 0);
#pragma unroll
        for (int r = 0; r < 8; ++r) acc2 = __builtin_amdgcn_mfma_f32_16x16x32_bf16(a[r],  wh2[r], acc2, 0, 0, 0);
        acc0 = __builtin_amdgcn_mfma_f32_16x16x32_bf16(ab1, wbh,  acc0, 0, 0, 0);
        acc1 = __builtin_amdgcn_mfma_f32_16x16x32_bf16(ab2, wbh,  acc1, 0, 0, 0);
        acc2 = __builtin_amdgcn_mfma_f32_16x16x32_bf16(ab1, wbh2, acc2, 0, 0, 0);
        f32x4 acc = acc0 + acc1 + acc2;

        f32x4 bacc = {0.f, 0.f, 0.f, 0.f};
        if (m < 4) {
            bf16x8 s0, s1, u0, u1;   // static select (avoid runtime-indexed regs -> scratch)
            if      (jt == 0) { s0 = a[0]; s1 = a[1]; u0 = a2[0]; u1 = a2[1]; }
            else if (jt == 1) { s0 = a[2]; s1 = a[3]; u0 = a2[2]; u1 = a2[3]; }
            else if (jt == 2) { s0 = a[4]; s1 = a[5]; u0 = a2[4]; u1 = a2[5]; }
            else              { s0 = a[6]; s1 = a[7]; u0 = a2[6]; u1 = a2[7]; }
            f32x4 b0 = {0.f, 0.f, 0.f, 0.f}, b1 = b0;
            b0 = __builtin_amdgcn_mfma_f32_16x16x32_bf16(s0, whb0,  b0, 0, 0, 0);
            b1 = __builtin_amdgcn_mfma_f32_16x16x32_bf16(s1, whb1,  b1, 0, 0, 0);
            b0 = __builtin_amdgcn_mfma_f32_16x16x32_bf16(u0, whb0,  b0, 0, 0, 0);
            b1 = __builtin_amdgcn_mfma_f32_16x16x32_bf16(u1, whb1,  b1, 0, 0, 0);
            b0 = __builtin_amdgcn_mfma_f32_16x16x32_bf16(s0, whb0l, b0, 0, 0, 0);
            b1 = __builtin_amdgcn_mfma_f32_16x16x32_bf16(s1, whb1l, b1, 0, 0, 0);
            bacc = b0 + b1;
        }

        if (kh) lds_h[jt][l] = acc;
        if (m < 4) lds_b[ww][l] = bacc;
        __syncthreads();                               // [E] partials ready

        float hnv[4] = {0.f, 0.f, 0.f, 0.f};
        float bnv[4] = {0.f, 0.f, 0.f, 0.f};

        // ---- issue ALL exchange stores (h by kh==0 waves; body by wave 0) ----
        if (!kh) {
            f32x4 oth = lds_h[jt][l];
            f32x4 sum = acc + oth;
            if (lq < 2) {
                unsigned short* q1 = (unsigned short*)(xg + ((p ^ 1) * 2 + 0) * 16384)
                                     + (lq * 4) * HID + jg;
                unsigned short* q2 = (unsigned short*)(xg + ((p ^ 1) * 2 + 1) * 16384)
                                     + (lq * 4) * HID + jg;
                unsigned short hh[4], hl[4];
#pragma unroll
                for (int i = 0; i < 4; ++i) {
                    float pre = sum[i] + cpre[i];
                    float rl = fmaxf(pre, 0.f);
                    float hv = 0.9f * hst[i] + 0.1f * rl;
                    hst[i] = hv; hnv[i] = hv;
                    hh[i] = f2bf(hv); hl[i] = f2bf(hv - b2f(hh[i]));
                }
                // write-through to IF$ (visible cross-XCD once vmcnt-drained)
                ST16_SYS(q1, 0,    hh[0]); ST16_SYS(q1, 1024, hh[1]);
                ST16_SYS(q1, 2048, hh[2]); ST16_SYS(q1, 3072, hh[3]);
                ST16_SYS(q2, 0,    hl[0]); ST16_SYS(q2, 1024, hl[1]);
                ST16_SYS(q2, 2048, hl[2]); ST16_SYS(q2, 3072, hl[3]);
            }
        }
        if (ww == 0 && m < 4) {
            f32x4 bs = lds_b[0][l];
#pragma unroll
            for (int s = 1; s < 8; ++s) bs += lds_b[s][l];
            if (lq < 2) {
                int jb = m * 16 + lr;
                unsigned short* r1 = (unsigned short*)(xg + 65536 + ((p ^ 1) * 2 + 0) * 2048)
                                     + (lq * 4) * BODYD + jb;
                unsigned short* r2 = (unsigned short*)(xg + 65536 + ((p ^ 1) * 2 + 1) * 2048)
                                     + (lq * 4) * BODYD + jb;
                unsigned short bh[4], blo[4];
#pragma unroll
                for (int i = 0; i < 4; ++i) {
                    float bn = bst[i] * maskv + ALPHA_F * (bs[i] + bhbv);
                    bst[i] = bn; bnv[i] = bn;
                    bh[i] = f2bf(bn); blo[i] = f2bf(bn - b2f(bh[i]));
                }
                ST16_SYS(r1, 0,   bh[0]);  ST16_SYS(r1, 128, bh[1]);
                ST16_SYS(r1, 256, bh[2]);  ST16_SYS(r1, 384, bh[3]);
                ST16_SYS(r2, 0,   blo[0]); ST16_SYS(r2, 128, blo[1]);
                ST16_SYS(r2, 256, blo[2]); ST16_SYS(r2, 384, blo[3]);
            }
        }

        // ---- counter-based release: each writer wave drains its OWN stores
        // (wave 0's drain covers h AND body), bumps the LDS counter; the
        // 4th writer to finish publishes the SINGLE member flag. No barrier.
        if (!kh) {
            asm volatile("s_waitcnt vmcnt(0)" ::: "memory");
            if (l == 0) {
                unsigned int old = atomicAdd(&rel_cnt, 1u);
                if (old == (unsigned int)(4 * t + 3)) {
                    __hip_atomic_store(flg_self, (unsigned int)(t + 1),
                                       __ATOMIC_RELAXED, __HIP_MEMORY_SCOPE_SYSTEM);
                }
            }
            // deferred NT output writes (not needed by peers) overlap peers' polls
            if (lq < 2) {
#pragma unroll
                for (int i = 0; i < 4; ++i)
                    __builtin_nontemporal_store(hnv[i], op + (size_t)(lq * 4 + i) * HID);
            }
        }
        if (ww == 0 && m < 4 && lq < 2) {
            int jb = m * 16 + lr;
#pragma unroll
            for (int i = 0; i < 4; ++i) {
                int mi = lq * 4 + i;
                __builtin_nontemporal_store(
                    bnv[i],
                    out + BODY_OFF + (size_t)t * (NB * BODYD) + (size_t)(g * 8 + mi) * BODYD + jb);
            }
        }
        // no [F] barrier: [C]/[E] of the next iteration provide all intra-block
        // ordering (stgb/lds_h/lds_b writes happen only after [C'], which waits
        // for every wave to finish this step's epilogue).
    }

    // h_fin = final h
    if (!kh && lq < 2) {
#pragma unroll
        for (int i = 0; i < 4; ++i) {
            int mi = lq * 4 + i;
            __builtin_nontemporal_store(hst[i], out + FIN_OFF + (size_t)(g * 8 + mi) * HID + jg);
        }
    }
}

extern "C" void kernel_launch(void* const* d_in, const int* in_sizes, int n_in,
                              void* d_out, int out_size, void* d_ws, size_t ws_size,
                              hipStream_t stream) {
    const float* x    = (const float*)d_in[0];
    const float* Wi2h = (const float*)d_in[1];
    const float* bi2h = (const float*)d_in[2];
    const float* Whh  = (const float*)d_in[3];
    const float* bh2h = (const float*)d_in[4];
    const float* Wb2h = (const float*)d_in[5];
    const float* bb2h = (const float*)d_in[6];
    const float* Wh2b = (const float*)d_in[7];
    const float* bh2b = (const float*)d_in[8];
    const float* mask = (const float*)d_in[9];
    float* out = (float*)d_out;
    unsigned char* ws = (unsigned char*)d_ws;

    init_kernel<<<256, 256, 0, stream>>>(Wi2h, bi2h, Whh, bh2h, Wb2h, bb2h, Wh2b, ws);
    xproj_kernel<<<dim3(2048, 4), 256, 0, stream>>>(x, out, ws);

    void* kargs[] = { (void*)&out, (void*)&ws, (void*)&bh2b, (void*)&mask };
    hipLaunchCooperativeKernel((void*)rnn_kernel, dim3(256), dim3(512), kargs, 0, stream);
}